// Round 8
// baseline (327.707 us; speedup 1.0000x reference)
//
#include <hip/hip_runtime.h>
#include <hip/hip_cooperative_groups.h>

// ---------------------------------------------------------------------------
// Session history:
//  R1: atomic dump to L3-resident out = 135 us (cross-XCD atomic RMW serializes).
//  R2/R3: bin store-path variants neutral (not the bottleneck).
//  R0-R3 accounting: {fill 41, pack 1.5, bin ~38, agg 10, red 6, GAP ~13-15/disp}.
//  R4: mega 354 us (spin storm). R5: mega 144 us (fence storm) -> hand-rolled
//      sync machinery costs ~60 us. R6: dropping consumer inv -> hang (poison
//      lines in consumer L2; invalidate is load-bearing).
//  R7: pack fused per-block = +18 us (types re-read 512x = 410 MB vs 25.6 MB
//      packed). Pack is a bandwidth amortizer. Bin counters: VALU 31%, HBM 12%,
//      occ 66% -> latency-bound; bank conflicts negligible.
//  R8 (this): ONE cooperative kernel {pack|sync|bin|sync|agg|sync|red} via
//      hipLaunchCooperativeKernel + grid.sync() (harness-supported, correct
//      clustered release/acquire incl. the invalidate R6 lacked). 5 -> 2
//      dispatches. Grid = exactly 512 co-resident blocks (proven R4/R5).
// ---------------------------------------------------------------------------

namespace cg = cooperative_groups;

#define TPB_PACK  256
#define P1_BLOCKS 512
#define P1_TPB    1024
#define SB_BITS   14
#define SBS       (1 << SB_BITS)     // atoms per super-bucket (16384)
#define NS_FUSE   13                 // coop path: natoms <= 13*16384 = 212992
#define NS_MAX    16
#define P2_TPB    1024
#define R_SUB     39                 // 13*39=507 agg work items (R13: fewer regressed)
#define TPB_RED   256
#define CAP_MAX   1024

// log-spaced energy table: r = 2^(L0 + k*HL), k in [0,256]; 258 entries/type (pad)
#define TAB_N   258
#define TAB_L0  (-3.3219281f)        // log2(0.1)
#define TAB_HL  (0.017157490f)       // (log2(2.1)-log2(0.1))/256
#define TAB_INV (58.283567f)         // 1/TAB_HL
#define TAB_OFF (193.61423f)         // -L0*TAB_INV

// =============================================================================
// COOPERATIVE MEGAKERNEL: pack -> bin -> agg -> red with grid.sync() barriers.
// Grid MUST be exactly 512 blocks (2/CU x 256): LDS ~69.8KB -> 2 blocks/CU,
// __launch_bounds__(1024,8) caps VGPR<=64 -> 32 waves/CU. Proven resident R4/R5.
// =============================================================================
__global__ __launch_bounds__(P1_TPB, 8) void zbl_coop(
    const float* __restrict__ rij,
    const float* __restrict__ rcov,
    const float* __restrict__ znum,
    const int*  __restrict__ fa,
    const int*  __restrict__ sa,
    const int*  __restrict__ types,
    unsigned int* __restrict__ packed,   // [nwords]
    unsigned int* __restrict__ regions,  // [P1_BLOCKS][NS][cap]
    int*   __restrict__ counts,          // [(NS+1)][P1_BLOCKS]; row NS = ovf counts
    uint2* __restrict__ ovf,             // [P1_BLOCKS][ovfStride]
    float* __restrict__ partials,        // [NS][R_SUB][SBS]
    float* __restrict__ out,
    int E, int nquad, int natoms, int nwords, int NS, int cap, int chunkQ,
    int ovfStride)
{
    cg::grid_group grid = cg::this_grid();

    __shared__ union {
        struct { unsigned pk[NS_FUSE * SBS / 16]; float tabE[16 * TAB_N]; } a; // 69.8 KB
        float  acc[SBS];                                                       // 64 KB
        float4 acc4[SBS / 4];
    } u;
    __shared__ float4 cB[16];
    __shared__ float4 cS[16];
    __shared__ float  cC[16];
    __shared__ int    scnt[NS_MAX];
    __shared__ int    s_ovfn;
    __shared__ int    s_any;

    const int b   = blockIdx.x;
    const int tid = threadIdx.x;

    // ---------------- phase A: pack types ONCE, grid-distributed -------------
    // Each of 512 blocks packs <=26 interleaved words; total reads = natoms (one
    // pass over types, ~800 KB grid-wide -- NOT per-block like R7's 410 MB).
    for (int w = b + P1_BLOCKS * tid; w < nwords; w += P1_BLOCKS * P1_TPB) {
        unsigned word = 0;
        if (((w << 4) + 16) <= natoms) {
            const int4* t4 = (const int4*)types;
            int b4 = w << 2;
            #pragma unroll
            for (int g = 0; g < 4; ++g) {
                int4 v = t4[b4 + g];
                word |= ((unsigned)v.x & 3u) << (8 * g + 0);
                word |= ((unsigned)v.y & 3u) << (8 * g + 2);
                word |= ((unsigned)v.z & 3u) << (8 * g + 4);
                word |= ((unsigned)v.w & 3u) << (8 * g + 6);
            }
        } else {
            int base = w << 4;
            for (int j = 0; j < 16; ++j) {
                int i = base + j;
                unsigned t = (i < natoms) ? (unsigned)types[i] : 0u;
                word |= (t & 3u) << (2 * j);
            }
        }
        packed[w] = word;
    }

    if (tid < NS)  scnt[tid] = 0;
    if (tid == 32) s_ovfn = 0;

    // per-pair constants (independent of phase A)
    if (tid < 16) {
        const float cc[4] = {0.02817f, 0.28022f, 0.50986f, 0.18175f};
        const float dd[4] = {0.20162f, 0.4029f, 0.94229f, 3.1998f};
        const float COUL = 14.399645478425668f;
        int t = tid;
        int ti = t >> 2, tj = t & 3;
        float zi = znum[ti], zj = znum[tj];
        float rc = rcov[ti] + rcov[tj];
        float a = 0.4685f / (powf(zi, 0.23f) + powf(zj, 0.23f));
        float inva = 1.0f / a;
        float factor = COUL * zi * zj;
        float da[4], ee[4];
        float phi = 0.0f, dphi = 0.0f, d2phi = 0.0f;
        #pragma unroll
        for (int k = 0; k < 4; ++k) {
            da[k] = dd[k] * inva;
            ee[k] = expf(-rc * da[k]);
            phi   += cc[k] * ee[k];
            dphi  -= cc[k] * da[k] * ee[k];
            d2phi += cc[k] * da[k] * da[k] * ee[k];
        }
        float invrc = 1.0f / rc;
        float ec   = factor * invrc * phi;
        float dec  = factor * invrc * (-phi * invrc + dphi);
        float d2ec = factor * invrc * (d2phi - 2.0f * invrc * dphi + 2.0f * phi * invrc * invrc);
        float A = (-3.0f * dec + rc * d2ec) * invrc * invrc;
        float B = (2.0f * dec - rc * d2ec) * invrc * invrc * invrc;
        float Cc = -ec + 0.5f * rc * dec - rc * rc * d2ec * (1.0f / 12.0f);
        const float L2E = 1.4426950408889634f;
        cB[t] = make_float4(rc, 0.5f * factor, A * (1.0f / 6.0f), B * 0.125f);
        cS[t] = make_float4(-da[0] * L2E, -da[1] * L2E, -da[2] * L2E, -da[3] * L2E);
        cC[t] = Cc * 0.5f;
    }
    __syncthreads();

    // build per-type energy table (needs cB/cS/cC only; overlaps phase-A drain)
    {
        const float lc0 = -5.1497481f;   // log2(0.02817)
        const float lc1 = -1.8353434f;   // log2(0.28022)
        const float lc2 = -0.9718340f;   // log2(0.50986)
        const float lc3 = -2.4600449f;   // log2(0.18175)
        for (int n = tid; n < 16 * TAB_N; n += P1_TPB) {
            int t = n / TAB_N, k = n - t * TAB_N;
            float v = 0.0f;
            if (k <= 256) {
                float r = exp2f(__builtin_fmaf((float)k, TAB_HL, TAB_L0));
                float4 B = cB[t];
                if (r <= B.x) {
                    float4 S = cS[t];
                    float p = exp2f(__builtin_fmaf(r, S.x, lc0))
                            + exp2f(__builtin_fmaf(r, S.y, lc1))
                            + exp2f(__builtin_fmaf(r, S.z, lc2))
                            + exp2f(__builtin_fmaf(r, S.w, lc3));
                    float r3 = r * r * r;
                    float poly = __builtin_fmaf(__builtin_fmaf(B.w, r, B.z), r3, cC[t]);
                    v = __builtin_fmaf(B.y * p, 1.0f / r, poly);
                }
            }
            u.a.tabE[n] = v;
        }
    }

    grid.sync();                          // packed[] visible grid-wide

    // ---------------- phase B: bin (legacy structure) ------------------------
    {
        // packed -> LDS, coalesced (25.6 MB grid-wide from L2, like legacy bin)
        for (int w = tid; w < nwords; w += P1_TPB)
            u.a.pk[w] = packed[w];
        __syncthreads();

        const float4* rij4 = (const float4*)rij;
        const int4*   fa4  = (const int4*)fa;
        const int4*   sa4  = (const int4*)sa;
        int myreg = b * NS;
        int q0 = b * chunkQ;
        int q1 = q0 + chunkQ; if (q1 > nquad) q1 = nquad;

        for (int q = q0 + tid; q < q1; q += P1_TPB) {
            float4 rv = rij4[q];
            int4   iv = fa4[q];
            int4   jv = sa4[q];
            float ra[4] = {rv.x, rv.y, rv.z, rv.w};
            int   ia[4] = {iv.x, iv.y, iv.z, iv.w};
            int   ja[4] = {jv.x, jv.y, jv.z, jv.w};
            float eo[4];
            #pragma unroll
            for (int k = 0; k < 4; ++k) {
                int i = ia[k], j = ja[k];
                unsigned wi = u.a.pk[i >> 4], wj = u.a.pk[j >> 4];
                unsigned ti = (wi >> ((i & 15) * 2)) & 3u;
                unsigned tj = (wj >> ((j & 15) * 2)) & 3u;
                int t = (int)((ti << 2) | tj);
                float kf = __builtin_fmaf(__log2f(ra[k]), TAB_INV, TAB_OFF);
                int ki = (int)kf;
                ki = ki < 0 ? 0 : (ki > 256 ? 256 : ki);
                float frac = kf - (float)ki;
                int base = t * TAB_N + ki;
                float v0 = u.a.tabE[base];
                float v1 = u.a.tabE[base + 1];
                eo[k] = __builtin_fmaf(v1 - v0, frac, v0);
            }
            #pragma unroll
            for (int k = 0; k < 4; ++k) {
                if (eo[k] != 0.0f) {
                    int atom = ia[k];
                    int s = atom >> SB_BITS;
                    int slot = atomicAdd(&scnt[s], 1);
                    if (slot < cap) {
                        unsigned rec = ((__float_as_uint(eo[k]) + 0x2000u) & 0xFFFFC000u)
                                     | (unsigned)(atom & (SBS - 1));
                        regions[(unsigned)((myreg + s) * cap + slot)] = rec;
                    } else {
                        int o = atomicAdd(&s_ovfn, 1);   // block-local list, no init
                        ovf[(size_t)b * ovfStride + o] =
                            make_uint2(__float_as_uint(eo[k]), (unsigned)atom);
                    }
                }
            }
        }

        // tail edges (E % 4): block 0, into its overflow list (<=3 entries)
        if (b == 0) {
            for (int idx = nquad * 4 + tid; idx < E; idx += P1_TPB) {
                int i = fa[idx], j = sa[idx];
                unsigned wi = u.a.pk[i >> 4], wj = u.a.pk[j >> 4];
                int t = (int)((((wi >> ((i & 15) * 2)) & 3u) << 2) |
                               ((wj >> ((j & 15) * 2)) & 3u));
                float r = rij[idx];
                float kf = __builtin_fmaf(__log2f(r), TAB_INV, TAB_OFF);
                int ki = (int)kf;
                ki = ki < 0 ? 0 : (ki > 256 ? 256 : ki);
                float frac = kf - (float)ki;
                int base = t * TAB_N + ki;
                float e = __builtin_fmaf(u.a.tabE[base + 1] - u.a.tabE[base], frac,
                                         u.a.tabE[base]);
                if (e != 0.0f) {
                    int o = atomicAdd(&s_ovfn, 1);
                    ovf[(size_t)b * ovfStride + o] =
                        make_uint2(__float_as_uint(e), (unsigned)i);
                }
            }
        }

        __syncthreads();
        if (tid < NS)  counts[tid * P1_BLOCKS + b] = min(scnt[tid], cap);
        if (tid == NS) counts[NS  * P1_BLOCKS + b] = s_ovfn;
    }

    grid.sync();                          // counts/regions/ovf visible grid-wide

    // ---------------- phase C: agg (blocks 0..NS*R_SUB-1) --------------------
    if (b < NS * R_SUB) {
        int s = b / R_SUB, r = b % R_SUB;
        for (int i = tid; i < SBS / 4; i += P1_TPB)
            u.acc4[i] = make_float4(0.f, 0.f, 0.f, 0.f);
        __syncthreads();

        int wave = tid >> 6;
        int lane = tid & 63;
        const int NW = P1_TPB >> 6;       // 16 waves
        for (int p = r + wave * R_SUB; p < P1_BLOCKS; p += NW * R_SUB) {
            int n = counts[s * P1_BLOCKS + p];            // wave-uniform
            size_t base = ((size_t)p * NS + s) * (size_t)cap;
            for (int t = lane; t < n; t += 64) {
                unsigned rec = regions[base + t];         // coalesced 256 B/wave
                atomicAdd(&u.acc[rec & (SBS - 1)],
                          __uint_as_float(rec & 0xFFFFC000u));
            }
        }
        __syncthreads();

        float4* dst4 = (float4*)(partials + ((size_t)s * R_SUB + r) * SBS);
        for (int i = tid; i < SBS / 4; i += P1_TPB)
            dst4[i] = u.acc4[i];
    }

    grid.sync();                          // partials visible grid-wide

    // ---------------- phase D: slice reduction -> out ------------------------
    {
        int nq  = natoms >> 2;
        int qpb = (nq + P1_BLOCKS - 1) / P1_BLOCKS;      // ~98 quads/block
        int qlo = b * qpb, qhi = qlo + qpb;
        if (qlo > nq) qlo = nq;
        if (qhi > nq) qhi = nq;
        bool own_tail = (b == P1_BLOCKS - 1);

        // overflow detection (typical: 0 -> rare path fully skipped)
        if (tid == 0) s_any = 0;
        __syncthreads();
        for (int p0 = tid; p0 < P1_BLOCKS; p0 += P1_TPB) {
            int n = counts[NS * P1_BLOCKS + p0];
            if (n > 0) atomicAdd(&s_any, n);
        }
        __syncthreads();

        for (int q = qlo + tid; q < qhi; q += P1_TPB) {
            int atom0 = q << 2;
            int s = atom0 >> SB_BITS, i = atom0 & (SBS - 1);
            const float* p = partials + (size_t)s * R_SUB * SBS + i;
            float4 acc = make_float4(0.f, 0.f, 0.f, 0.f);
            #pragma unroll
            for (int k = 0; k < R_SUB; ++k) {
                float4 v = *(const float4*)(p + (size_t)k * SBS);
                acc.x += v.x; acc.y += v.y; acc.z += v.z; acc.w += v.w;
            }
            if (s_any > 0) {              // rare, correctness-only path
                for (int pp = 0; pp < P1_BLOCKS; ++pp) {
                    int n = counts[NS * P1_BLOCKS + pp];
                    const uint2* lst = ovf + (size_t)pp * ovfStride;
                    for (int e = 0; e < n; ++e) {
                        uint2 rec = lst[e];
                        int d = (int)rec.y - atom0;
                        if ((unsigned)d < 4u) {
                            float v = __uint_as_float(rec.x);
                            if      (d == 0) acc.x += v;
                            else if (d == 1) acc.y += v;
                            else if (d == 2) acc.z += v;
                            else             acc.w += v;
                        }
                    }
                }
            }
            *(float4*)(out + atom0) = acc;
        }

        // scalar tail atoms (natoms % 4): last block
        if (own_tail) {
            for (int atom = (nq << 2) + tid; atom < natoms; atom += P1_TPB) {
                int s = atom >> SB_BITS, i = atom & (SBS - 1);
                const float* p = partials + (size_t)s * R_SUB * SBS + i;
                float a = 0.f;
                #pragma unroll
                for (int k = 0; k < R_SUB; ++k) a += p[(size_t)k * SBS];
                if (s_any > 0) {
                    for (int pp = 0; pp < P1_BLOCKS; ++pp) {
                        int n = counts[NS * P1_BLOCKS + pp];
                        const uint2* lst = ovf + (size_t)pp * ovfStride;
                        for (int e = 0; e < n; ++e)
                            if ((int)lst[e].y == atom) a += __uint_as_float(lst[e].x);
                    }
                }
                out[atom] = a;
            }
        }
    }
}

// =============================================================================
// LEGACY PATH (fallback: coop launch refused, natoms too big, tiny ws) — R3.
// =============================================================================
__global__ __launch_bounds__(TPB_PACK) void zbl_pack(
    const int* __restrict__ types, unsigned int* __restrict__ packed,
    float* __restrict__ fallback, int natoms, int nwords)
{
    int tid = blockIdx.x * TPB_PACK + threadIdx.x;
    int nth = gridDim.x * TPB_PACK;
    for (int w = tid; w < nwords; w += nth) {
        int base = w << 4;
        unsigned int word = 0;
        #pragma unroll
        for (int j = 0; j < 16; ++j) {
            int i = base + j;
            unsigned int t = (i < natoms) ? (unsigned int)types[i] : 0u;
            word |= (t & 3u) << (2 * j);
        }
        packed[w] = word;
    }
    for (int i = tid; i < natoms; i += nth) fallback[i] = 0.0f;
}

__global__ __launch_bounds__(P1_TPB) void zbl_bin(
    const float* __restrict__ rij, const float* __restrict__ rcov,
    const float* __restrict__ znum, const int* __restrict__ fa,
    const int* __restrict__ sa, const unsigned int* __restrict__ packed,
    unsigned int* __restrict__ regions, int* __restrict__ counts,
    float* __restrict__ fallback,
    int E, int nquad, int natoms, int nwords, int NS, int cap, int chunkQ)
{
    extern __shared__ unsigned int s_packed[];
    __shared__ float  tabE[16 * TAB_N];
    __shared__ float4 cB[16];
    __shared__ float4 cS[16];
    __shared__ float  cC[16];
    __shared__ int scnt[NS_MAX];

    for (int w = threadIdx.x; w < nwords; w += P1_TPB) s_packed[w] = packed[w];
    if (threadIdx.x < NS) scnt[threadIdx.x] = 0;

    if (threadIdx.x < 16) {
        const float cc[4] = {0.02817f, 0.28022f, 0.50986f, 0.18175f};
        const float dd[4] = {0.20162f, 0.4029f, 0.94229f, 3.1998f};
        const float COUL = 14.399645478425668f;
        int t = threadIdx.x;
        int ti = t >> 2, tj = t & 3;
        float zi = znum[ti], zj = znum[tj];
        float rc = rcov[ti] + rcov[tj];
        float a = 0.4685f / (powf(zi, 0.23f) + powf(zj, 0.23f));
        float inva = 1.0f / a;
        float factor = COUL * zi * zj;
        float da[4], ee[4];
        float phi = 0.0f, dphi = 0.0f, d2phi = 0.0f;
        #pragma unroll
        for (int k = 0; k < 4; ++k) {
            da[k] = dd[k] * inva;
            ee[k] = expf(-rc * da[k]);
            phi   += cc[k] * ee[k];
            dphi  -= cc[k] * da[k] * ee[k];
            d2phi += cc[k] * da[k] * da[k] * ee[k];
        }
        float invrc = 1.0f / rc;
        float ec   = factor * invrc * phi;
        float dec  = factor * invrc * (-phi * invrc + dphi);
        float d2ec = factor * invrc * (d2phi - 2.0f * invrc * dphi + 2.0f * phi * invrc * invrc);
        float A = (-3.0f * dec + rc * d2ec) * invrc * invrc;
        float B = (2.0f * dec - rc * d2ec) * invrc * invrc * invrc;
        float Cc = -ec + 0.5f * rc * dec - rc * rc * d2ec * (1.0f / 12.0f);
        const float L2E = 1.4426950408889634f;
        cB[t] = make_float4(rc, 0.5f * factor, A * (1.0f / 6.0f), B * 0.125f);
        cS[t] = make_float4(-da[0] * L2E, -da[1] * L2E, -da[2] * L2E, -da[3] * L2E);
        cC[t] = Cc * 0.5f;
    }
    __syncthreads();

    const float lc0 = -5.1497481f, lc1 = -1.8353434f;
    const float lc2 = -0.9718340f, lc3 = -2.4600449f;

    for (int n = threadIdx.x; n < 16 * TAB_N; n += P1_TPB) {
        int t = n / TAB_N, k = n - t * TAB_N;
        float v = 0.0f;
        if (k <= 256) {
            float r = exp2f(__builtin_fmaf((float)k, TAB_HL, TAB_L0));
            float4 B = cB[t];
            if (r <= B.x) {
                float4 S = cS[t];
                float p = exp2f(__builtin_fmaf(r, S.x, lc0))
                        + exp2f(__builtin_fmaf(r, S.y, lc1))
                        + exp2f(__builtin_fmaf(r, S.z, lc2))
                        + exp2f(__builtin_fmaf(r, S.w, lc3));
                float r3 = r * r * r;
                float poly = __builtin_fmaf(__builtin_fmaf(B.w, r, B.z), r3, cC[t]);
                v = __builtin_fmaf(B.y * p, 1.0f / r, poly);
            }
        }
        tabE[n] = v;
    }
    __syncthreads();

    const float4* rij4 = (const float4*)rij;
    const int4*   fa4  = (const int4*)fa;
    const int4*   sa4  = (const int4*)sa;
    int myreg = blockIdx.x * NS;
    int q0 = blockIdx.x * chunkQ;
    int q1 = q0 + chunkQ; if (q1 > nquad) q1 = nquad;

    for (int q = q0 + threadIdx.x; q < q1; q += P1_TPB) {
        float4 rv = rij4[q];
        int4   iv = fa4[q];
        int4   jv = sa4[q];
        float ra[4] = {rv.x, rv.y, rv.z, rv.w};
        int   ia[4] = {iv.x, iv.y, iv.z, iv.w};
        int   ja[4] = {jv.x, jv.y, jv.z, jv.w};
        float eo[4];
        #pragma unroll
        for (int k = 0; k < 4; ++k) {
            int i = ia[k], j = ja[k];
            unsigned int wi = s_packed[i >> 4], wj = s_packed[j >> 4];
            unsigned int ti = (wi >> ((i & 15) * 2)) & 3u;
            unsigned int tj = (wj >> ((j & 15) * 2)) & 3u;
            int t = (int)((ti << 2) | tj);
            float kf = __builtin_fmaf(__log2f(ra[k]), TAB_INV, TAB_OFF);
            int ki = (int)kf;
            ki = ki < 0 ? 0 : (ki > 256 ? 256 : ki);
            float frac = kf - (float)ki;
            int base = t * TAB_N + ki;
            float v0 = tabE[base], v1 = tabE[base + 1];
            eo[k] = __builtin_fmaf(v1 - v0, frac, v0);
        }
        #pragma unroll
        for (int k = 0; k < 4; ++k) {
            if (eo[k] != 0.0f) {
                int atom = ia[k];
                int s = atom >> SB_BITS;
                int slot = atomicAdd(&scnt[s], 1);
                if (slot < cap) {
                    unsigned rec = ((__float_as_uint(eo[k]) + 0x2000u) & 0xFFFFC000u)
                                 | (unsigned)(atom & (SBS - 1));
                    regions[(unsigned)((myreg + s) * cap + slot)] = rec;
                } else {
                    unsafeAtomicAdd(&fallback[atom], eo[k]);
                }
            }
        }
    }

    if (blockIdx.x == 0) {
        for (int idx = nquad * 4 + threadIdx.x; idx < E; idx += P1_TPB) {
            int i = fa[idx], j = sa[idx];
            unsigned int wi = s_packed[i >> 4], wj = s_packed[j >> 4];
            int t = (int)((((wi >> ((i & 15) * 2)) & 3u) << 2) |
                           ((wj >> ((j & 15) * 2)) & 3u));
            float r = rij[idx];
            float kf = __builtin_fmaf(__log2f(r), TAB_INV, TAB_OFF);
            int ki = (int)kf;
            ki = ki < 0 ? 0 : (ki > 256 ? 256 : ki);
            float frac = kf - (float)ki;
            int base = t * TAB_N + ki;
            float e = __builtin_fmaf(tabE[base + 1] - tabE[base], frac, tabE[base]);
            if (e != 0.0f) unsafeAtomicAdd(&fallback[i], e);
        }
    }

    __syncthreads();
    if (cap > 0 && threadIdx.x < NS)
        counts[threadIdx.x * P1_BLOCKS + blockIdx.x] = min(scnt[threadIdx.x], cap);
}

__global__ __launch_bounds__(P2_TPB) void zbl_agg(
    const unsigned int* __restrict__ regions, const int* __restrict__ counts,
    float* __restrict__ partials, int NS, int cap)
{
    __shared__ float acc[SBS];
    int s = blockIdx.x, r = blockIdx.y;
    float4* acc4 = (float4*)acc;
    for (int i = threadIdx.x; i < SBS / 4; i += P2_TPB)
        acc4[i] = make_float4(0.f, 0.f, 0.f, 0.f);
    __syncthreads();
    int wave = threadIdx.x >> 6, lane = threadIdx.x & 63;
    const int NW = P2_TPB >> 6;
    for (int p = r + wave * R_SUB; p < P1_BLOCKS; p += NW * R_SUB) {
        int n = counts[s * P1_BLOCKS + p];
        size_t base = ((size_t)p * NS + s) * (size_t)cap;
        for (int t = lane; t < n; t += 64) {
            unsigned rec = regions[base + t];
            atomicAdd(&acc[rec & (SBS - 1)], __uint_as_float(rec & 0xFFFFC000u));
        }
    }
    __syncthreads();
    float4* dst4 = (float4*)(partials + ((size_t)s * R_SUB + r) * SBS);
    for (int i = threadIdx.x; i < SBS / 4; i += P2_TPB)
        dst4[i] = acc4[i];
}

__global__ __launch_bounds__(TPB_RED) void zbl_red(
    const float* __restrict__ partials, const float* __restrict__ fallback,
    float* __restrict__ out, int natoms)
{
    int q = blockIdx.x * TPB_RED + threadIdx.x;
    int nq = natoms >> 2;
    if (q < nq) {
        int atom = q << 2;
        int s = atom >> SB_BITS, i = atom & (SBS - 1);
        const float4* fb4 = (const float4*)(fallback + atom);
        float4 acc = *fb4;
        const float* p = partials + (size_t)s * R_SUB * SBS + i;
        #pragma unroll
        for (int k = 0; k < R_SUB; ++k) {
            float4 v = *(const float4*)(p + (size_t)k * SBS);
            acc.x += v.x; acc.y += v.y; acc.z += v.z; acc.w += v.w;
        }
        *(float4*)(out + atom) = acc;
    }
    if (blockIdx.x == 0 && threadIdx.x < (natoms & 3)) {
        int atom = (nq << 2) + threadIdx.x;
        int s = atom >> SB_BITS, i = atom & (SBS - 1);
        float acc = fallback[atom];
        const float* p = partials + (size_t)s * R_SUB * SBS + i;
        #pragma unroll
        for (int k = 0; k < R_SUB; ++k) acc += p[(size_t)k * SBS];
        out[atom] = acc;
    }
}

// =============================================================================
static inline size_t al256(size_t x) { return (x + 255) & ~(size_t)255; }

static void launch_legacy(const float* rij, const float* rcov, const float* znum,
                          const int* fa, const int* sa, const int* types,
                          float* out, void* d_ws, size_t ws_size,
                          int E, int nquad, int natoms, int nwords, int NS,
                          int chunkQ, hipStream_t stream)
{
    size_t packed_bytes = al256((size_t)nwords * 4);
    size_t cnt_bytes    = al256((size_t)NS * P1_BLOCKS * 4);
    size_t fb_bytes     = al256((size_t)natoms * 4);
    size_t part_bytes   = al256((size_t)NS * R_SUB * SBS * 4);
    unsigned int* packed = (unsigned int*)d_ws;
    int*   counts   = (int*)  ((char*)d_ws + packed_bytes);
    float* fallback = (float*)((char*)d_ws + packed_bytes + cnt_bytes);
    float* partials = (float*)((char*)d_ws + packed_bytes + cnt_bytes + fb_bytes);
    unsigned int* regions = (unsigned int*)((char*)d_ws + packed_bytes + cnt_bytes
                                            + fb_bytes + part_bytes);
    long long avail = (long long)ws_size
                    - (long long)(packed_bytes + cnt_bytes + fb_bytes + part_bytes);
    int cap = 0;
    if (avail > 0) cap = (int)(avail / ((long long)P1_BLOCKS * (long long)NS * 4));
    if (cap > CAP_MAX) cap = CAP_MAX;
    size_t smem = (size_t)nwords * sizeof(unsigned int);

    if (cap >= 64) {
        zbl_pack<<<96, TPB_PACK, 0, stream>>>(types, packed, fallback, natoms, nwords);
        zbl_bin<<<P1_BLOCKS, P1_TPB, smem, stream>>>(
            rij, rcov, znum, fa, sa, packed, regions, counts, fallback,
            E, nquad, natoms, nwords, NS, cap, chunkQ);
        dim3 g2(NS, R_SUB);
        zbl_agg<<<g2, P2_TPB, 0, stream>>>(regions, counts, partials, NS, cap);
        int nq = natoms >> 2;
        zbl_red<<<(nq + TPB_RED - 1) / TPB_RED, TPB_RED, 0, stream>>>(
            partials, fallback, out, natoms);
    } else {
        zbl_pack<<<96, TPB_PACK, 0, stream>>>(types, packed, out, natoms, nwords);
        zbl_bin<<<P1_BLOCKS, P1_TPB, smem, stream>>>(
            rij, rcov, znum, fa, sa, packed, regions, counts, out,
            E, nquad, natoms, nwords, NS, 0, chunkQ);
    }
}

extern "C" void kernel_launch(void* const* d_in, const int* in_sizes, int n_in,
                              void* d_out, int out_size, void* d_ws, size_t ws_size,
                              hipStream_t stream) {
    const float* rij  = (const float*)d_in[0];
    const float* rcov = (const float*)d_in[1];
    const float* znum = (const float*)d_in[2];
    const int*   fa   = (const int*)d_in[3];
    const int*   sa   = (const int*)d_in[4];
    const int*   types= (const int*)d_in[5];
    float* out = (float*)d_out;
    int E = in_sizes[0];
    int natoms = out_size;
    int nquad = E / 4;
    int nwords = (natoms + 15) / 16;
    int NS = (natoms + SBS - 1) >> SB_BITS;      // 13 for 200K atoms
    if (NS > NS_MAX) NS = NS_MAX;
    int chunkQ = (nquad + P1_BLOCKS - 1) / P1_BLOCKS;
    int ovfStride = chunkQ * 4 + 8;

    if (natoms <= NS_FUSE * SBS) {
        // --- coop layout: [packed][counts][ovf][partials][regions]
        size_t packed_b = al256((size_t)nwords * 4);
        size_t cnt_b    = al256((size_t)(NS + 1) * P1_BLOCKS * 4);
        size_t ovf_b    = al256((size_t)P1_BLOCKS * ovfStride * 8);
        size_t part_b   = al256((size_t)NS * R_SUB * SBS * 4);
        char* base = (char*)d_ws;
        unsigned int* packed = (unsigned int*)base;          base += packed_b;
        int*   counts   = (int*)base;                        base += cnt_b;
        uint2* ovf      = (uint2*)base;                      base += ovf_b;
        float* partials = (float*)base;                      base += part_b;
        unsigned int* regions = (unsigned int*)base;

        long long avail = (long long)ws_size
                        - (long long)(packed_b + cnt_b + ovf_b + part_b);
        int cap = 0;
        if (avail > 0) cap = (int)(avail / ((long long)P1_BLOCKS * NS * 4));
        if (cap > CAP_MAX) cap = CAP_MAX;

        if (cap >= 64) {
            void* args[] = {
                (void*)&rij, (void*)&rcov, (void*)&znum,
                (void*)&fa, (void*)&sa, (void*)&types,
                (void*)&packed, (void*)&regions, (void*)&counts, (void*)&ovf,
                (void*)&partials, (void*)&out,
                (void*)&E, (void*)&nquad, (void*)&natoms, (void*)&nwords,
                (void*)&NS, (void*)&cap, (void*)&chunkQ, (void*)&ovfStride
            };
            hipError_t err = hipLaunchCooperativeKernel(
                (const void*)zbl_coop, dim3(P1_BLOCKS), dim3(P1_TPB),
                args, 0, stream);
            if (err == hipSuccess) return;
            // cooperative launch refused -> fall through to legacy pipeline
        }
    }

    launch_legacy(rij, rcov, znum, fa, sa, types, out, d_ws, ws_size,
                  E, nquad, natoms, nwords, NS, chunkQ, stream);
}

// Round 9
// 161.539 us; speedup vs baseline: 2.0287x; 2.0287x over previous
//
#include <hip/hip_runtime.h>

// ---------------------------------------------------------------------------
// Session history:
//  R1: atomic dump to L3-resident out = 135 us (cross-XCD atomic RMW serializes
//      at the coherence point). Keep streaming partials.
//  R2/R3: scnt-alloc variants neutral -> bin DS-atomic/store path not the lever.
//  R0-R3 accounting: {fill 41, pack 1.5, bin ~38, agg 10, red 6, GAP ~13/disp}.
//  R4-R8: ALL in-kernel grid-sync forms lose to kernel-boundary coherence:
//      spin flags 354, release flags 144, grid.sync() 228 (coop) — each routes
//      through LLC-scope cache maintenance across 8 non-coherent L2s. The
//      ~13 us/dispatch gap is cheaper than any in-kernel replacement. CLOSED.
//  R7: per-block type re-read costs +18 us (410 MB vs 25.6 MB) — pack kernel
//      is a bandwidth amortizer, keep it. Bin counters: VALU 31%, HBM 12%,
//      occ 66% -> LATENCY-bound; bank conflicts negligible.
//  R9 (this): R3 pipeline + software-pipelined bin main loop (prefetch next
//      iteration's rij4/fa4/sa4 before processing current; ~3 iters/thread,
//      loads are independent across iterations). agg (5.9 TB/s) and red
//      (5.5 TB/s) are already at bandwidth — untouched.
// ---------------------------------------------------------------------------

#define TPB_PACK  256
#define P1_BLOCKS 512
#define P1_TPB    1024
#define SB_BITS   14
#define SBS       (1 << SB_BITS)     // atoms per super-bucket (16384)
#define NS_MAX    16
#define P2_TPB    1024
#define R_SUB     39                 // 13*39=507 blocks; fewer regressed (latency)
#define TPB_RED   256
#define CAP_MAX   1024

// log-spaced energy table: r = 2^(L0 + k*HL), k in [0,256]; 258 entries/type (pad)
#define TAB_N   258
#define TAB_L0  (-3.3219281f)        // log2(0.1)
#define TAB_HL  (0.017157490f)       // (log2(2.1)-log2(0.1))/256
#define TAB_INV (58.283567f)         // 1/TAB_HL
#define TAB_OFF (193.61423f)         // -L0*TAB_INV

// ---- pack atom types (2 bits each) AND zero the fallback accumulator ----
__global__ __launch_bounds__(TPB_PACK) void zbl_pack(
    const int* __restrict__ types, unsigned int* __restrict__ packed,
    float* __restrict__ fallback, int natoms, int nwords)
{
    int tid = blockIdx.x * TPB_PACK + threadIdx.x;
    int nth = gridDim.x * TPB_PACK;
    for (int w = tid; w < nwords; w += nth) {
        int base = w << 4;
        unsigned int word = 0;
        #pragma unroll
        for (int j = 0; j < 16; ++j) {
            int i = base + j;
            unsigned int t = (i < natoms) ? (unsigned int)types[i] : 0u;
            word |= (t & 3u) << (2 * j);
        }
        packed[w] = word;
    }
    for (int i = tid; i < natoms; i += nth) fallback[i] = 0.0f;
}

// ------- Phase 1: tabulated e(r,t); software-pipelined edge loop -------
__global__ __launch_bounds__(P1_TPB) void zbl_bin(
    const float* __restrict__ rij,
    const float* __restrict__ rcov,
    const float* __restrict__ znum,
    const int*  __restrict__ fa,
    const int*  __restrict__ sa,
    const unsigned int* __restrict__ packed,
    unsigned int* __restrict__ regions,  // [P1_BLOCKS][NS][cap] 4 B records
    int*   __restrict__ counts,          // [NS][P1_BLOCKS] (transposed)
    float* __restrict__ fallback,        // natoms floats, pre-zeroed (= d_out if cap==0)
    int E, int nquad, int natoms, int nwords, int NS, int cap, int chunkQ)
{
    extern __shared__ unsigned int s_packed[];   // nwords words (~50 KB)
    __shared__ float  tabE[16 * TAB_N];          // 16.5 KB energy table
    __shared__ float4 cB[16];                    // {rc, f/2, A/6, B/8}
    __shared__ float4 cS[16];                    // exp2 slopes
    __shared__ float  cC[16];                    // C/2
    __shared__ int scnt[NS_MAX];

    for (int w = threadIdx.x; w < nwords; w += P1_TPB)
        s_packed[w] = packed[w];                 // coalesced, L2-resident
    if (threadIdx.x < NS) scnt[threadIdx.x] = 0;

    if (threadIdx.x < 16) {
        const float cc[4] = {0.02817f, 0.28022f, 0.50986f, 0.18175f};
        const float dd[4] = {0.20162f, 0.4029f, 0.94229f, 3.1998f};
        const float COUL = 14.399645478425668f;
        int t = threadIdx.x;
        int ti = t >> 2, tj = t & 3;
        float zi = znum[ti], zj = znum[tj];
        float rc = rcov[ti] + rcov[tj];
        float a = 0.4685f / (powf(zi, 0.23f) + powf(zj, 0.23f));
        float inva = 1.0f / a;
        float factor = COUL * zi * zj;
        float da[4], ee[4];
        float phi = 0.0f, dphi = 0.0f, d2phi = 0.0f;
        #pragma unroll
        for (int k = 0; k < 4; ++k) {
            da[k] = dd[k] * inva;
            ee[k] = expf(-rc * da[k]);
            phi   += cc[k] * ee[k];
            dphi  -= cc[k] * da[k] * ee[k];
            d2phi += cc[k] * da[k] * da[k] * ee[k];
        }
        float invrc = 1.0f / rc;
        float ec   = factor * invrc * phi;
        float dec  = factor * invrc * (-phi * invrc + dphi);
        float d2ec = factor * invrc * (d2phi - 2.0f * invrc * dphi + 2.0f * phi * invrc * invrc);
        float A = (-3.0f * dec + rc * d2ec) * invrc * invrc;
        float B = (2.0f * dec - rc * d2ec) * invrc * invrc * invrc;
        float Cc = -ec + 0.5f * rc * dec - rc * rc * d2ec * (1.0f / 12.0f);
        const float L2E = 1.4426950408889634f;
        cB[t] = make_float4(rc, 0.5f * factor, A * (1.0f / 6.0f), B * 0.125f);
        cS[t] = make_float4(-da[0] * L2E, -da[1] * L2E, -da[2] * L2E, -da[3] * L2E);
        cC[t] = Cc * 0.5f;
    }
    __syncthreads();

    const float lc0 = -5.1497481f;   // log2(0.02817)
    const float lc1 = -1.8353434f;   // log2(0.28022)
    const float lc2 = -0.9718340f;   // log2(0.50986)
    const float lc3 = -2.4600449f;   // log2(0.18175)

    // build the per-type energy table (once per block)
    for (int n = threadIdx.x; n < 16 * TAB_N; n += P1_TPB) {
        int t = n / TAB_N, k = n - t * TAB_N;
        float v = 0.0f;
        if (k <= 256) {
            float r = exp2f(__builtin_fmaf((float)k, TAB_HL, TAB_L0));
            float4 B = cB[t];
            if (r <= B.x) {
                float4 S = cS[t];
                float p = exp2f(__builtin_fmaf(r, S.x, lc0))
                        + exp2f(__builtin_fmaf(r, S.y, lc1))
                        + exp2f(__builtin_fmaf(r, S.z, lc2))
                        + exp2f(__builtin_fmaf(r, S.w, lc3));
                float r3 = r * r * r;
                float poly = __builtin_fmaf(__builtin_fmaf(B.w, r, B.z), r3, cC[t]);
                v = __builtin_fmaf(B.y * p, 1.0f / r, poly);
            }
        }
        tabE[n] = v;
    }
    __syncthreads();

    const float4* rij4 = (const float4*)rij;
    const int4*   fa4  = (const int4*)fa;
    const int4*   sa4  = (const int4*)sa;

    int myreg = blockIdx.x * NS;                 // 32-bit region indexing

    int q0 = blockIdx.x * chunkQ;
    int q1 = q0 + chunkQ; if (q1 > nquad) q1 = nquad;

    // -------- software-pipelined main loop: prefetch iter i+1's loads --------
    // Per thread only ~3 iterations; without this, each iteration's ~600-cy
    // L3/HBM latency is fully exposed (R7 counters: latency-bound, VALU 31%).
    int q = q0 + threadIdx.x;
    float4 rv;  int4 iv, jv;
    if (q < q1) { rv = rij4[q]; iv = fa4[q]; jv = sa4[q]; }
    while (q < q1) {
        int qn = q + P1_TPB;
        float4 rvn;  int4 ivn, jvn;
        if (qn < q1) { rvn = rij4[qn]; ivn = fa4[qn]; jvn = sa4[qn]; }  // prefetch

        float ra[4] = {rv.x, rv.y, rv.z, rv.w};
        int   ia[4] = {iv.x, iv.y, iv.z, iv.w};
        int   ja[4] = {jv.x, jv.y, jv.z, jv.w};
        float eo[4];
        #pragma unroll
        for (int k = 0; k < 4; ++k) {
            int i = ia[k], j = ja[k];
            unsigned int wi = s_packed[i >> 4], wj = s_packed[j >> 4];
            unsigned int ti = (wi >> ((i & 15) * 2)) & 3u;
            unsigned int tj = (wj >> ((j & 15) * 2)) & 3u;
            int t = (int)((ti << 2) | tj);
            // log-spaced table lookup: branchless, no exp, no rc test
            float kf = __builtin_fmaf(__log2f(ra[k]), TAB_INV, TAB_OFF);
            int ki = (int)kf;
            ki = ki < 0 ? 0 : (ki > 256 ? 256 : ki);
            float frac = kf - (float)ki;
            int base = t * TAB_N + ki;
            float v0 = tabE[base];          // ds_read2_b32 pair
            float v1 = tabE[base + 1];
            eo[k] = __builtin_fmaf(v1 - v0, frac, v0);
        }
        // batched slot allocation (R3 form): 4 independent DS atomics -> one wait
        int sbk[4], slot[4];
        #pragma unroll
        for (int k = 0; k < 4; ++k) {
            sbk[k]  = ia[k] >> SB_BITS;
            slot[k] = (eo[k] != 0.0f) ? atomicAdd(&scnt[sbk[k]], 1) : CAP_MAX;
        }
        #pragma unroll
        for (int k = 0; k < 4; ++k) {
            if (eo[k] != 0.0f) {
                if (slot[k] < cap) {
                    unsigned rec = ((__float_as_uint(eo[k]) + 0x2000u) & 0xFFFFC000u)
                                 | (unsigned)(ia[k] & (SBS - 1));
                    regions[(unsigned)((myreg + sbk[k]) * cap + slot[k])] = rec;
                } else {
                    unsafeAtomicAdd(&fallback[ia[k]], eo[k]);   // rare overflow
                }
            }
        }

        rv = rvn; iv = ivn; jv = jvn;
        q = qn;
    }

    // tail (E % 4 != 0): straight to fallback (at most 3 edges)
    if (blockIdx.x == 0) {
        for (int idx = nquad * 4 + threadIdx.x; idx < E; idx += P1_TPB) {
            int i = fa[idx], j = sa[idx];
            unsigned int wi = s_packed[i >> 4], wj = s_packed[j >> 4];
            int t = (int)((((wi >> ((i & 15) * 2)) & 3u) << 2) |
                           ((wj >> ((j & 15) * 2)) & 3u));
            float r = rij[idx];
            float kf = __builtin_fmaf(__log2f(r), TAB_INV, TAB_OFF);
            int ki = (int)kf;
            ki = ki < 0 ? 0 : (ki > 256 ? 256 : ki);
            float frac = kf - (float)ki;
            int base = t * TAB_N + ki;
            float v0 = tabE[base], v1 = tabE[base + 1];
            float e = __builtin_fmaf(v1 - v0, frac, v0);
            if (e != 0.0f) unsafeAtomicAdd(&fallback[i], e);
        }
    }

    __syncthreads();
    if (cap > 0 && threadIdx.x < NS)
        counts[threadIdx.x * P1_BLOCKS + blockIdx.x] = min(scnt[threadIdx.x], cap);
}

// ------- Phase 2: (super-bucket, replica) -> 64 KB LDS accumulator -------
// Wave-parallel over producers; 59 MB at ~5.9 TB/s — at bandwidth. Untouched.
__global__ __launch_bounds__(P2_TPB) void zbl_agg(
    const unsigned int* __restrict__ regions,
    const int*  __restrict__ counts,     // [NS][P1_BLOCKS]
    float* __restrict__ partials,        // [NS][R_SUB][SBS]
    int NS, int cap)
{
    __shared__ float acc[SBS];           // 64 KB -> 2 blocks/CU
    int s = blockIdx.x;                  // super-bucket
    int r = blockIdx.y;                  // replica

    float4* acc4 = (float4*)acc;
    for (int i = threadIdx.x; i < SBS / 4; i += P2_TPB)
        acc4[i] = make_float4(0.f, 0.f, 0.f, 0.f);
    __syncthreads();

    int wave = threadIdx.x >> 6;
    int lane = threadIdx.x & 63;
    const int NW = P2_TPB >> 6;          // 16 waves
    for (int p = r + wave * R_SUB; p < P1_BLOCKS; p += NW * R_SUB) {
        int n = counts[s * P1_BLOCKS + p];               // wave-uniform load
        size_t base = ((size_t)p * NS + s) * (size_t)cap;
        for (int t = lane; t < n; t += 64) {
            unsigned rec = regions[base + t];            // coalesced 256 B/wave
            atomicAdd(&acc[rec & (SBS - 1)],
                      __uint_as_float(rec & 0xFFFFC000u));   // ds_add_f32
        }
    }
    __syncthreads();

    float4* dst4 = (float4*)(partials + ((size_t)s * R_SUB + r) * SBS);
    for (int i = threadIdx.x; i < SBS / 4; i += P2_TPB)
        dst4[i] = acc4[i];
}

// ------- Phase 3: reduce R_SUB partials + fallback -> out (float4 lanes) -------
// 33 MB at ~5.5 TB/s — at bandwidth. Untouched.
__global__ __launch_bounds__(TPB_RED) void zbl_red(
    const float* __restrict__ partials,
    const float* __restrict__ fallback,
    float* __restrict__ out,
    int natoms)
{
    int q = blockIdx.x * TPB_RED + threadIdx.x;      // quad-of-atoms index
    int nq = natoms >> 2;
    if (q < nq) {
        int atom = q << 2;
        int s = atom >> SB_BITS, i = atom & (SBS - 1);   // SBS%4==0: quad never crosses buckets
        const float4* fb4 = (const float4*)(fallback + atom);
        float4 acc = *fb4;
        const float* p = partials + (size_t)s * R_SUB * SBS + i;
        #pragma unroll
        for (int k = 0; k < R_SUB; ++k) {
            float4 v = *(const float4*)(p + (size_t)k * SBS);
            acc.x += v.x; acc.y += v.y; acc.z += v.z; acc.w += v.w;
        }
        *(float4*)(out + atom) = acc;
    }
    // scalar tail (natoms % 4)
    if (blockIdx.x == 0 && threadIdx.x < (natoms & 3)) {
        int atom = (nq << 2) + threadIdx.x;
        int s = atom >> SB_BITS, i = atom & (SBS - 1);
        float acc = fallback[atom];
        const float* p = partials + (size_t)s * R_SUB * SBS + i;
        #pragma unroll
        for (int k = 0; k < R_SUB; ++k) acc += p[(size_t)k * SBS];
        out[atom] = acc;
    }
}

extern "C" void kernel_launch(void* const* d_in, const int* in_sizes, int n_in,
                              void* d_out, int out_size, void* d_ws, size_t ws_size,
                              hipStream_t stream) {
    const float* rij  = (const float*)d_in[0];
    const float* rcov = (const float*)d_in[1];
    const float* znum = (const float*)d_in[2];
    const int*   fa   = (const int*)d_in[3];
    const int*   sa   = (const int*)d_in[4];
    const int*   types= (const int*)d_in[5];
    float* out = (float*)d_out;
    int E = in_sizes[0];
    int natoms = out_size;
    int nquad = E / 4;
    int nwords = (natoms + 15) / 16;
    int NS = (natoms + SBS - 1) >> SB_BITS;      // 13 for 200K atoms
    if (NS > NS_MAX) NS = NS_MAX;                // (natoms <= 256K)
    int chunkQ = (nquad + P1_BLOCKS - 1) / P1_BLOCKS;

    // ws layout: [packed][counts][fallback][partials][regions...]
    size_t packed_bytes = ((size_t)nwords * 4 + 255) & ~(size_t)255;
    size_t cnt_bytes    = ((size_t)NS * P1_BLOCKS * 4 + 255) & ~(size_t)255;
    size_t fb_bytes     = ((size_t)natoms * 4 + 255) & ~(size_t)255;
    size_t part_bytes   = ((size_t)NS * R_SUB * SBS * 4 + 255) & ~(size_t)255;
    unsigned int* packed = (unsigned int*)d_ws;
    int*   counts   = (int*)  ((char*)d_ws + packed_bytes);
    float* fallback = (float*)((char*)d_ws + packed_bytes + cnt_bytes);
    float* partials = (float*)((char*)d_ws + packed_bytes + cnt_bytes + fb_bytes);
    unsigned int* regions = (unsigned int*)((char*)d_ws + packed_bytes + cnt_bytes
                                            + fb_bytes + part_bytes);

    long long avail = (long long)ws_size
                    - (long long)(packed_bytes + cnt_bytes + fb_bytes + part_bytes);
    int cap = 0;
    if (avail > 0) cap = (int)(avail / ((long long)P1_BLOCKS * (long long)NS * 4));
    if (cap > CAP_MAX) cap = CAP_MAX;

    size_t smem = (size_t)nwords * sizeof(unsigned int);

    if (cap >= 64) {
        zbl_pack<<<96, TPB_PACK, 0, stream>>>(types, packed, fallback, natoms, nwords);
        zbl_bin<<<P1_BLOCKS, P1_TPB, smem, stream>>>(
            rij, rcov, znum, fa, sa, packed, regions, counts, fallback,
            E, nquad, natoms, nwords, NS, cap, chunkQ);
        dim3 g2(NS, R_SUB);
        zbl_agg<<<g2, P2_TPB, 0, stream>>>(regions, counts, partials, NS, cap);
        int nq = natoms >> 2;
        zbl_red<<<(nq + TPB_RED - 1) / TPB_RED, TPB_RED, 0, stream>>>(
            partials, fallback, out, natoms);
    } else {
        // ws too small: everything overflows straight into out (correct, slow)
        zbl_pack<<<96, TPB_PACK, 0, stream>>>(types, packed, out, natoms, nwords);
        zbl_bin<<<P1_BLOCKS, P1_TPB, smem, stream>>>(
            rij, rcov, znum, fa, sa, packed, regions, counts, out,
            E, nquad, natoms, nwords, NS, 0, chunkQ);
    }
}